// Round 1
// baseline (599.782 us; speedup 1.0000x reference)
//
#include <hip/hip_runtime.h>
#include <math.h>

#define NN 50000
#define NE 800000
#define INF 128
#define H 64

// ---------------- degree / CSR build ----------------
__global__ __launch_bounds__(256) void k_count(const int* __restrict__ dst, int* __restrict__ cnt, int E) {
  int e = blockIdx.x * 256 + threadIdx.x;
  if (e < E) atomicAdd(&cnt[dst[e]], 1);
}

__global__ __launch_bounds__(256) void k_dinv(const int* __restrict__ cnt, float* __restrict__ dinv, int N) {
  int i = blockIdx.x * 256 + threadIdx.x;
  if (i < N) {
    float d = (float)(cnt[i] < 1 ? 1 : cnt[i]);
    dinv[i] = 1.0f / sqrtf(d);
  }
}

__global__ __launch_bounds__(1024) void k_scan1(const int* __restrict__ cnt, int* __restrict__ off,
                                                int* __restrict__ bsum, int N) {
  __shared__ int sh[1024];
  int t = threadIdx.x;
  int i = blockIdx.x * 1024 + t;
  int v = (i < N) ? cnt[i] : 0;
  sh[t] = v;
  __syncthreads();
  for (int d = 1; d < 1024; d <<= 1) {
    int x = (t >= d) ? sh[t - d] : 0;
    __syncthreads();
    sh[t] += x;
    __syncthreads();
  }
  if (i < N) off[i] = sh[t] - v;          // exclusive within block
  if (t == 1023) bsum[blockIdx.x] = sh[t]; // block total
}

__global__ void k_scan2(const int* __restrict__ bsum, int* __restrict__ btop, int nb) {
  if (threadIdx.x == 0 && blockIdx.x == 0) {
    int run = 0;
    for (int b = 0; b < nb; ++b) { btop[b] = run; run += bsum[b]; }
  }
}

__global__ __launch_bounds__(1024) void k_scan3(int* __restrict__ off, const int* __restrict__ btop,
                                                int* __restrict__ cursor, int N) {
  int i = blockIdx.x * 1024 + threadIdx.x;
  if (i < N) {
    int v = off[i] + btop[blockIdx.x];
    off[i] = v;
    cursor[i] = v;
  }
}

__global__ __launch_bounds__(256) void k_fill(const int* __restrict__ src, const int* __restrict__ dst,
                                              int* __restrict__ cursor, int* __restrict__ csr_src, int E) {
  int e = blockIdx.x * 256 + threadIdx.x;
  if (e < E) {
    int d = dst[e];
    int p = atomicAdd(&cursor[d], 1);
    csr_src[p] = src[e];
  }
}

// ---------------- SpMM (gather form, deterministic) ----------------
// out[n][f] = alpha * dinv[n] * sum_{s in in-edges(n)} dinv[s]*in[s][f]   (+ beta*aux[n][f])
__global__ __launch_bounds__(256) void k_spmm(const float* __restrict__ in, int ldin,
                                              float* __restrict__ out, int ldout,
                                              const float* __restrict__ aux, int ldaux,
                                              const int* __restrict__ off, const int* __restrict__ csr_src,
                                              const float* __restrict__ dinv,
                                              float alpha, float beta, int use_aux, int N, int E) {
  int wid = (blockIdx.x * 256 + threadIdx.x) >> 6;
  int lane = threadIdx.x & 63;
  if (wid >= N) return;
  int jb = off[wid];
  int je = (wid + 1 < N) ? off[wid + 1] : E;
  float acc = 0.f;
  for (int j = jb; j < je; ++j) {
    int s = csr_src[j];
    acc = fmaf(in[(size_t)s * ldin + lane], dinv[s], acc);
  }
  float v = alpha * dinv[wid] * acc;
  if (use_aux) v = fmaf(beta, aux[(size_t)wid * ldaux + lane], v);
  out[(size_t)wid * ldout + lane] = v;
}

// ---------------- dense GEMM: out[N,64] = act(A[N,K] @ W[64,K]^T + b) ----------------
__global__ __launch_bounds__(256) void k_gemm64(const float* __restrict__ A, int lda, int K,
                                                const float* __restrict__ W,
                                                const float* __restrict__ bias,
                                                float* __restrict__ out, int ldo,
                                                int N, int do_relu) {
  __shared__ float As[32][68];  // As[kk][row], pad 68 keeps b128 16B-aligned, banks OK
  __shared__ float Bs[32][64];  // Bs[kk][col]
  const int tid = threadIdx.x;
  const int r0 = blockIdx.x * 64;
  const int tr = tid >> 4;  // 0..15 -> rows 4*tr..4*tr+3
  const int tc = tid & 15;  // 0..15 -> cols 4*tc..4*tc+3
  float acc[4][4] = {{0.f}};

  for (int k0 = 0; k0 < K; k0 += 32) {
#pragma unroll
    for (int q = 0; q < 2; ++q) {  // stage A (transpose into LDS)
      int idx = tid + q * 256;
      int row = idx >> 3;
      int jj = idx & 7;
      int gr = r0 + row;
      float4 v = make_float4(0.f, 0.f, 0.f, 0.f);
      if (gr < N) v = *(const float4*)(A + (size_t)gr * lda + k0 + jj * 4);
      As[jj * 4 + 0][row] = v.x;
      As[jj * 4 + 1][row] = v.y;
      As[jj * 4 + 2][row] = v.z;
      As[jj * 4 + 3][row] = v.w;
    }
#pragma unroll
    for (int q = 0; q < 2; ++q) {  // stage B (transpose W into LDS)
      int idx = tid + q * 256;
      int col = idx & 63;
      int jb = idx >> 6;  // 0..7
      float4 v = *(const float4*)(W + (size_t)col * K + k0 + jb * 4);
      Bs[jb * 4 + 0][col] = v.x;
      Bs[jb * 4 + 1][col] = v.y;
      Bs[jb * 4 + 2][col] = v.z;
      Bs[jb * 4 + 3][col] = v.w;
    }
    __syncthreads();
#pragma unroll
    for (int kk = 0; kk < 32; ++kk) {
      float4 a = *(const float4*)(&As[kk][tr * 4]);
      float4 b = *(const float4*)(&Bs[kk][tc * 4]);
      float av[4] = {a.x, a.y, a.z, a.w};
      float bv[4] = {b.x, b.y, b.z, b.w};
#pragma unroll
      for (int i = 0; i < 4; ++i)
#pragma unroll
        for (int j = 0; j < 4; ++j) acc[i][j] = fmaf(av[i], bv[j], acc[i][j]);
    }
    __syncthreads();
  }

  float4 bb = *(const float4*)(bias + tc * 4);
  float bv[4] = {bb.x, bb.y, bb.z, bb.w};
#pragma unroll
  for (int i = 0; i < 4; ++i) {
    int row = r0 + tr * 4 + i;
    if (row < N) {
      float4 o;
      float t0 = acc[i][0] + bv[0];
      float t1 = acc[i][1] + bv[1];
      float t2 = acc[i][2] + bv[2];
      float t3 = acc[i][3] + bv[3];
      if (do_relu) {
        t0 = fmaxf(t0, 0.f); t1 = fmaxf(t1, 0.f);
        t2 = fmaxf(t2, 0.f); t3 = fmaxf(t3, 0.f);
      }
      o.x = t0; o.y = t1; o.z = t2; o.w = t3;
      *(float4*)(out + (size_t)row * ldo + tc * 4) = o;
    }
  }
}

// ---------------- head: out[N,2] = h[N,64] @ W4[2,64]^T + b4 ----------------
__global__ __launch_bounds__(256) void k_head(const float* __restrict__ h, int ldh,
                                              const float* __restrict__ W4, const float* __restrict__ b4,
                                              float* __restrict__ out, int N) {
  int wid = (blockIdx.x * 256 + threadIdx.x) >> 6;
  int lane = threadIdx.x & 63;
  if (wid >= N) return;
  float a = h[(size_t)wid * ldh + lane];
  float acc0 = a * W4[lane];
  float acc1 = a * W4[64 + lane];
#pragma unroll
  for (int o = 32; o > 0; o >>= 1) {
    acc0 += __shfl_xor(acc0, o);
    acc1 += __shfl_xor(acc1, o);
  }
  if (lane == 0) {
    out[(size_t)wid * 2 + 0] = acc0 + b4[0];
    out[(size_t)wid * 2 + 1] = acc1 + b4[1];
  }
}

extern "C" void kernel_launch(void* const* d_in, const int* in_sizes, int n_in,
                              void* d_out, int out_size, void* d_ws, size_t ws_size,
                              hipStream_t stream) {
  const float* in_feat = (const float*)d_in[0];
  const int* src = (const int*)d_in[1];
  const int* dst = (const int*)d_in[2];
  const float* W1 = (const float*)d_in[3];
  const float* b1 = (const float*)d_in[4];
  const float* W2 = (const float*)d_in[5];
  const float* b2 = (const float*)d_in[6];
  const float* Wc1 = (const float*)d_in[7];
  const float* bc1 = (const float*)d_in[8];
  const float* Wc2 = (const float*)d_in[9];
  const float* bc2 = (const float*)d_in[10];
  const float* W3 = (const float*)d_in[11];
  const float* b3 = (const float*)d_in[12];
  const float* W4 = (const float*)d_in[13];
  const float* b4 = (const float*)d_in[14];
  float* out = (float*)d_out;

  // workspace carve (256B aligned)
  char* ws = (char*)d_ws;
  size_t o = 0;
  auto carve = [&](size_t bytes) -> void* {
    o = (o + 255) & ~(size_t)255;
    void* p = ws + o;
    o += bytes;
    return p;
  };
  int* cnt = (int*)carve((size_t)NN * 4);
  int* off = (int*)carve((size_t)NN * 4);
  int* cursor = (int*)carve((size_t)NN * 4);
  int* bsum = (int*)carve(64 * 4);
  int* btop = (int*)carve(64 * 4);
  int* csr_src = (int*)carve((size_t)NE * 4);
  float* dinv = (float*)carve((size_t)NN * 4);
  float* h1 = (float*)carve((size_t)NN * H * 4);        // [N,64]
  float* X1buf = (float*)carve((size_t)NN * 3 * H * 4); // [N,192] = [X0|X1|X2] conv1
  float* X2buf = (float*)carve((size_t)NN * 3 * H * 4); // [N,192] conv2
  (void)ws_size; (void)in_sizes; (void)n_in; (void)out_size;

  const int NB_E = (NE + 255) / 256;      // 3125
  const int NB_N = (NN + 255) / 256;      // 196
  const int NB_S = (NN + 1023) / 1024;    // 49
  const int NB_W = (NN * 64 + 255) / 256; // wave-per-node kernels: 12500
  const int NB_G = (NN + 63) / 64;        // 782

  // degree + dinv + CSR
  hipMemsetAsync(cnt, 0, (size_t)NN * 4, stream);
  k_count<<<NB_E, 256, 0, stream>>>(dst, cnt, NE);
  k_dinv<<<NB_N, 256, 0, stream>>>(cnt, dinv, NN);
  k_scan1<<<NB_S, 1024, 0, stream>>>(cnt, off, bsum, NN);
  k_scan2<<<1, 64, 0, stream>>>(bsum, btop, NB_S);
  k_scan3<<<NB_S, 1024, 0, stream>>>(off, btop, cursor, NN);
  k_fill<<<NB_E, 256, 0, stream>>>(src, dst, cursor, csr_src, NE);

  // h1 = relu(in_feat @ W1^T + b1)
  k_gemm64<<<NB_G, 256, 0, stream>>>(in_feat, INF, INF, W1, b1, h1, H, NN, 1);
  // X0 = relu(h1 @ W2^T + b2) -> X1buf[:,0:64]
  k_gemm64<<<NB_G, 256, 0, stream>>>(h1, H, H, W2, b2, X1buf, 3 * H, NN, 1);
  // X1 = -A.X0 -> X1buf[:,64:128]
  k_spmm<<<NB_W, 256, 0, stream>>>(X1buf, 3 * H, X1buf + H, 3 * H, (const float*)nullptr, 0,
                                   off, csr_src, dinv, -1.f, 0.f, 0, NN, NE);
  // X2 = -2*A.X1 - X0 -> X1buf[:,128:192]
  k_spmm<<<NB_W, 256, 0, stream>>>(X1buf + H, 3 * H, X1buf + 2 * H, 3 * H, X1buf, 3 * H,
                                   off, csr_src, dinv, -2.f, -1.f, 1, NN, NE);
  // conv1 linear: X0' = relu(X1buf @ Wc1^T + bc1) -> X2buf[:,0:64]
  k_gemm64<<<NB_G, 256, 0, stream>>>(X1buf, 3 * H, 3 * H, Wc1, bc1, X2buf, 3 * H, NN, 1);
  // conv2 terms
  k_spmm<<<NB_W, 256, 0, stream>>>(X2buf, 3 * H, X2buf + H, 3 * H, (const float*)nullptr, 0,
                                   off, csr_src, dinv, -1.f, 0.f, 0, NN, NE);
  k_spmm<<<NB_W, 256, 0, stream>>>(X2buf + H, 3 * H, X2buf + 2 * H, 3 * H, X2buf, 3 * H,
                                   off, csr_src, dinv, -2.f, -1.f, 1, NN, NE);
  // conv2 linear -> h1 (reuse)
  k_gemm64<<<NB_G, 256, 0, stream>>>(X2buf, 3 * H, 3 * H, Wc2, bc2, h1, H, NN, 1);
  // h3 = relu(h1 @ W3^T + b3) -> X1buf[:,0:64] (reuse, stride 192)
  k_gemm64<<<NB_G, 256, 0, stream>>>(h1, H, H, W3, b3, X1buf, 3 * H, NN, 1);
  // head
  k_head<<<NB_W, 256, 0, stream>>>(X1buf, 3 * H, W4, b4, out, NN);
}

// Round 2
// 414.129 us; speedup vs baseline: 1.4483x; 1.4483x over previous
//
#include <hip/hip_runtime.h>
#include <math.h>

#define NN 50000
#define NE 800000
#define INF 128
#define H 64

// ---------------- degree / CSR build ----------------
__global__ __launch_bounds__(256) void k_count(const int* __restrict__ dst, int* __restrict__ cnt, int E) {
  int e = blockIdx.x * 256 + threadIdx.x;
  if (e < E) atomicAdd(&cnt[dst[e]], 1);
}

__global__ __launch_bounds__(256) void k_dinv(const int* __restrict__ cnt, float* __restrict__ dinv, int N) {
  int i = blockIdx.x * 256 + threadIdx.x;
  if (i < N) {
    float d = (float)(cnt[i] < 1 ? 1 : cnt[i]);
    dinv[i] = 1.0f / sqrtf(d);
  }
}

__global__ __launch_bounds__(1024) void k_scan1(const int* __restrict__ cnt, int* __restrict__ off,
                                                int* __restrict__ bsum, int N) {
  __shared__ int sh[1024];
  int t = threadIdx.x;
  int i = blockIdx.x * 1024 + t;
  int v = (i < N) ? cnt[i] : 0;
  sh[t] = v;
  __syncthreads();
  for (int d = 1; d < 1024; d <<= 1) {
    int x = (t >= d) ? sh[t - d] : 0;
    __syncthreads();
    sh[t] += x;
    __syncthreads();
  }
  if (i < N) off[i] = sh[t] - v;           // exclusive within block
  if (t == 1023) bsum[blockIdx.x] = sh[t]; // block total
}

__global__ void k_scan2(const int* __restrict__ bsum, int* __restrict__ btop, int nb) {
  if (threadIdx.x == 0 && blockIdx.x == 0) {
    int run = 0;
    for (int b = 0; b < nb; ++b) { btop[b] = run; run += bsum[b]; }
  }
}

__global__ __launch_bounds__(1024) void k_scan3(int* __restrict__ off, const int* __restrict__ btop,
                                                int* __restrict__ cursor, int N) {
  int i = blockIdx.x * 1024 + threadIdx.x;
  if (i < N) {
    int v = off[i] + btop[blockIdx.x];
    off[i] = v;
    cursor[i] = v;
  }
}

__global__ __launch_bounds__(256) void k_fill(const int* __restrict__ src, const int* __restrict__ dst,
                                              int* __restrict__ cursor, int* __restrict__ csr_src, int E) {
  int e = blockIdx.x * 256 + threadIdx.x;
  if (e < E) {
    int d = dst[e];
    int p = atomicAdd(&cursor[d], 1);
    csr_src[p] = src[e];
  }
}

// ---------------- SpMM v2 (gather, pre-scaled compact table, 4-way edge ILP) ----------------
// Sin: [N,64] scaled features (S = dinv .* X), stride 64.
// out[n][0:64] = alpha*dinv[n]*sum_s Sin[s]  (+ beta*aux[n])   -- stride ldo (pre-offset pointer)
// out_s (optional): dinv[n] * out[n], compact [N,64].
// Wave layout: 1 wave = 1 node; lane = (g<<4)|q, g=edge group 0..3, q=col quad 0..15.
__global__ __launch_bounds__(256) void k_spmm2(const float* __restrict__ Sin,
                                               float* __restrict__ out, int ldo,
                                               float* __restrict__ out_s,
                                               const float* __restrict__ aux, int ldaux,
                                               const int* __restrict__ off, const int* __restrict__ csr_src,
                                               const float* __restrict__ dinv,
                                               float alpha, float beta, int use_aux, int N, int E) {
  int wid = (blockIdx.x * 256 + threadIdx.x) >> 6;
  if (wid >= N) return;
  int lane = threadIdx.x & 63;
  int g = lane >> 4;          // edge group
  int c4 = (lane & 15) * 4;   // column quad base
  int jb = off[wid];
  int je = (wid + 1 < N) ? off[wid + 1] : E;

  float4 acc = make_float4(0.f, 0.f, 0.f, 0.f);
  int j = jb + g;
  // unroll-2: two independent index loads + two independent row loads in flight
  for (; j + 4 < je; j += 8) {
    int s0 = csr_src[j];
    int s1 = csr_src[j + 4];
    float4 v0 = *(const float4*)(Sin + (size_t)s0 * H + c4);
    float4 v1 = *(const float4*)(Sin + (size_t)s1 * H + c4);
    acc.x += v0.x + v1.x;
    acc.y += v0.y + v1.y;
    acc.z += v0.z + v1.z;
    acc.w += v0.w + v1.w;
  }
  if (j < je) {
    int s0 = csr_src[j];
    float4 v0 = *(const float4*)(Sin + (size_t)s0 * H + c4);
    acc.x += v0.x; acc.y += v0.y; acc.z += v0.z; acc.w += v0.w;
  }
  // reduce across the 4 edge groups (lanes xor 16, 32)
#pragma unroll
  for (int o = 16; o <= 32; o <<= 1) {
    acc.x += __shfl_xor(acc.x, o);
    acc.y += __shfl_xor(acc.y, o);
    acc.z += __shfl_xor(acc.z, o);
    acc.w += __shfl_xor(acc.w, o);
  }
  if (g == 0) {
    float dn = dinv[wid];
    float a = alpha * dn;
    float4 r;
    r.x = a * acc.x; r.y = a * acc.y; r.z = a * acc.z; r.w = a * acc.w;
    if (use_aux) {
      float4 x = *(const float4*)(aux + (size_t)wid * ldaux + c4);
      r.x = fmaf(beta, x.x, r.x);
      r.y = fmaf(beta, x.y, r.y);
      r.z = fmaf(beta, x.z, r.z);
      r.w = fmaf(beta, x.w, r.w);
    }
    *(float4*)(out + (size_t)wid * ldo + c4) = r;
    if (out_s) {
      float4 rs;
      rs.x = dn * r.x; rs.y = dn * r.y; rs.z = dn * r.z; rs.w = dn * r.w;
      *(float4*)(out_s + (size_t)wid * H + c4) = rs;
    }
  }
}

// ---------------- dense GEMM: out[N,64] = act(A[N,K] @ W[64,K]^T + b) ----------------
// Optional second output: out_s[n] = dinv[n] * out[n], compact [N,64].
__global__ __launch_bounds__(256) void k_gemm64(const float* __restrict__ A, int lda, int K,
                                                const float* __restrict__ W,
                                                const float* __restrict__ bias,
                                                float* __restrict__ out, int ldo,
                                                float* __restrict__ out_s,
                                                const float* __restrict__ dinv,
                                                int N, int do_relu) {
  __shared__ float As[32][68];
  __shared__ float Bs[32][64];
  const int tid = threadIdx.x;
  const int r0 = blockIdx.x * 64;
  const int tr = tid >> 4;
  const int tc = tid & 15;
  float acc[4][4] = {{0.f}};

  for (int k0 = 0; k0 < K; k0 += 32) {
#pragma unroll
    for (int q = 0; q < 2; ++q) {
      int idx = tid + q * 256;
      int row = idx >> 3;
      int jj = idx & 7;
      int gr = r0 + row;
      float4 v = make_float4(0.f, 0.f, 0.f, 0.f);
      if (gr < N) v = *(const float4*)(A + (size_t)gr * lda + k0 + jj * 4);
      As[jj * 4 + 0][row] = v.x;
      As[jj * 4 + 1][row] = v.y;
      As[jj * 4 + 2][row] = v.z;
      As[jj * 4 + 3][row] = v.w;
    }
#pragma unroll
    for (int q = 0; q < 2; ++q) {
      int idx = tid + q * 256;
      int col = idx & 63;
      int jb = idx >> 6;
      float4 v = *(const float4*)(W + (size_t)col * K + k0 + jb * 4);
      Bs[jb * 4 + 0][col] = v.x;
      Bs[jb * 4 + 1][col] = v.y;
      Bs[jb * 4 + 2][col] = v.z;
      Bs[jb * 4 + 3][col] = v.w;
    }
    __syncthreads();
#pragma unroll
    for (int kk = 0; kk < 32; ++kk) {
      float4 a = *(const float4*)(&As[kk][tr * 4]);
      float4 b = *(const float4*)(&Bs[kk][tc * 4]);
      float av[4] = {a.x, a.y, a.z, a.w};
      float bv[4] = {b.x, b.y, b.z, b.w};
#pragma unroll
      for (int i = 0; i < 4; ++i)
#pragma unroll
        for (int j = 0; j < 4; ++j) acc[i][j] = fmaf(av[i], bv[j], acc[i][j]);
    }
    __syncthreads();
  }

  float4 bb = *(const float4*)(bias + tc * 4);
  float bv[4] = {bb.x, bb.y, bb.z, bb.w};
#pragma unroll
  for (int i = 0; i < 4; ++i) {
    int row = r0 + tr * 4 + i;
    if (row < N) {
      float t0 = acc[i][0] + bv[0];
      float t1 = acc[i][1] + bv[1];
      float t2 = acc[i][2] + bv[2];
      float t3 = acc[i][3] + bv[3];
      if (do_relu) {
        t0 = fmaxf(t0, 0.f); t1 = fmaxf(t1, 0.f);
        t2 = fmaxf(t2, 0.f); t3 = fmaxf(t3, 0.f);
      }
      float4 o = make_float4(t0, t1, t2, t3);
      *(float4*)(out + (size_t)row * ldo + tc * 4) = o;
      if (out_s) {
        float dn = dinv[row];
        float4 os = make_float4(dn * t0, dn * t1, dn * t2, dn * t3);
        *(float4*)(out_s + (size_t)row * H + tc * 4) = os;
      }
    }
  }
}

// ---------------- head: out[N,2] = h[N,64] @ W4[2,64]^T + b4 ----------------
__global__ __launch_bounds__(256) void k_head(const float* __restrict__ h, int ldh,
                                              const float* __restrict__ W4, const float* __restrict__ b4,
                                              float* __restrict__ out, int N) {
  int wid = (blockIdx.x * 256 + threadIdx.x) >> 6;
  int lane = threadIdx.x & 63;
  if (wid >= N) return;
  float a = h[(size_t)wid * ldh + lane];
  float acc0 = a * W4[lane];
  float acc1 = a * W4[64 + lane];
#pragma unroll
  for (int o = 32; o > 0; o >>= 1) {
    acc0 += __shfl_xor(acc0, o);
    acc1 += __shfl_xor(acc1, o);
  }
  if (lane == 0) {
    out[(size_t)wid * 2 + 0] = acc0 + b4[0];
    out[(size_t)wid * 2 + 1] = acc1 + b4[1];
  }
}

extern "C" void kernel_launch(void* const* d_in, const int* in_sizes, int n_in,
                              void* d_out, int out_size, void* d_ws, size_t ws_size,
                              hipStream_t stream) {
  const float* in_feat = (const float*)d_in[0];
  const int* src = (const int*)d_in[1];
  const int* dst = (const int*)d_in[2];
  const float* W1 = (const float*)d_in[3];
  const float* b1 = (const float*)d_in[4];
  const float* W2 = (const float*)d_in[5];
  const float* b2 = (const float*)d_in[6];
  const float* Wc1 = (const float*)d_in[7];
  const float* bc1 = (const float*)d_in[8];
  const float* Wc2 = (const float*)d_in[9];
  const float* bc2 = (const float*)d_in[10];
  const float* W3 = (const float*)d_in[11];
  const float* b3 = (const float*)d_in[12];
  const float* W4 = (const float*)d_in[13];
  const float* b4 = (const float*)d_in[14];
  float* out = (float*)d_out;

  char* ws = (char*)d_ws;
  size_t o = 0;
  auto carve = [&](size_t bytes) -> void* {
    o = (o + 255) & ~(size_t)255;
    void* p = ws + o;
    o += bytes;
    return p;
  };
  int* cnt = (int*)carve((size_t)NN * 4);
  int* off = (int*)carve((size_t)NN * 4);
  int* cursor = (int*)carve((size_t)NN * 4);
  int* bsum = (int*)carve(64 * 4);
  int* btop = (int*)carve(64 * 4);
  int* csr_src = (int*)carve((size_t)NE * 4);
  float* dinv = (float*)carve((size_t)NN * 4);
  float* h1 = (float*)carve((size_t)NN * H * 4);        // [N,64]
  float* h2 = (float*)carve((size_t)NN * H * 4);        // [N,64]
  float* S0 = (float*)carve((size_t)NN * H * 4);        // scaled gather table A
  float* S1 = (float*)carve((size_t)NN * H * 4);        // scaled gather table B
  float* X1buf = (float*)carve((size_t)NN * 3 * H * 4); // [N,192] conv1 terms
  float* X2buf = (float*)carve((size_t)NN * 3 * H * 4); // [N,192] conv2 terms
  (void)ws_size; (void)in_sizes; (void)n_in; (void)out_size;

  const int NB_E = (NE + 255) / 256;
  const int NB_N = (NN + 255) / 256;
  const int NB_S = (NN + 1023) / 1024;
  const int NB_W = (NN * 64 + 255) / 256; // wave-per-node: 12500
  const int NB_G = (NN + 63) / 64;        // 782

  // degree + dinv + CSR
  hipMemsetAsync(cnt, 0, (size_t)NN * 4, stream);
  k_count<<<NB_E, 256, 0, stream>>>(dst, cnt, NE);
  k_dinv<<<NB_N, 256, 0, stream>>>(cnt, dinv, NN);
  k_scan1<<<NB_S, 1024, 0, stream>>>(cnt, off, bsum, NN);
  k_scan2<<<1, 64, 0, stream>>>(bsum, btop, NB_S);
  k_scan3<<<NB_S, 1024, 0, stream>>>(off, btop, cursor, NN);
  k_fill<<<NB_E, 256, 0, stream>>>(src, dst, cursor, csr_src, NE);

  // h1 = relu(in_feat @ W1^T + b1)
  k_gemm64<<<NB_G, 256, 0, stream>>>(in_feat, INF, INF, W1, b1, h1, H,
                                     (float*)nullptr, dinv, NN, 1);
  // X0 = relu(h1 @ W2^T + b2) -> X1buf[:,0:64]; scaled -> S0
  k_gemm64<<<NB_G, 256, 0, stream>>>(h1, H, H, W2, b2, X1buf, 3 * H, S0, dinv, NN, 1);
  // X1 = -A.X0 -> X1buf[:,64:128]; scaled -> S1
  k_spmm2<<<NB_W, 256, 0, stream>>>(S0, X1buf + H, 3 * H, S1, (const float*)nullptr, 0,
                                    off, csr_src, dinv, -1.f, 0.f, 0, NN, NE);
  // X2 = -2*A.X1 - X0 -> X1buf[:,128:192]
  k_spmm2<<<NB_W, 256, 0, stream>>>(S1, X1buf + 2 * H, 3 * H, (float*)nullptr, X1buf, 3 * H,
                                    off, csr_src, dinv, -2.f, -1.f, 1, NN, NE);
  // conv1 linear: X0' = relu(X1buf @ Wc1^T + bc1) -> X2buf[:,0:64]; scaled -> S0
  k_gemm64<<<NB_G, 256, 0, stream>>>(X1buf, 3 * H, 3 * H, Wc1, bc1, X2buf, 3 * H, S0, dinv, NN, 1);
  // conv2 terms
  k_spmm2<<<NB_W, 256, 0, stream>>>(S0, X2buf + H, 3 * H, S1, (const float*)nullptr, 0,
                                    off, csr_src, dinv, -1.f, 0.f, 0, NN, NE);
  k_spmm2<<<NB_W, 256, 0, stream>>>(S1, X2buf + 2 * H, 3 * H, (float*)nullptr, X2buf, 3 * H,
                                    off, csr_src, dinv, -2.f, -1.f, 1, NN, NE);
  // conv2 linear -> h1
  k_gemm64<<<NB_G, 256, 0, stream>>>(X2buf, 3 * H, 3 * H, Wc2, bc2, h1, H,
                                     (float*)nullptr, dinv, NN, 1);
  // h2 = relu(h1 @ W3^T + b3), compact [N,64]
  k_gemm64<<<NB_G, 256, 0, stream>>>(h1, H, H, W3, b3, h2, H,
                                     (float*)nullptr, dinv, NN, 1);
  // head
  k_head<<<NB_W, 256, 0, stream>>>(h2, H, W4, b4, out, NN);
}

// Round 3
// 411.512 us; speedup vs baseline: 1.4575x; 1.0064x over previous
//
#include <hip/hip_runtime.h>
#include <math.h>

#define NN 50000
#define NE 800000
#define INF 128
#define H 64
#define NPART 8
#define PSIZE ((NN + NPART - 1) / NPART)  // 6250
#define EPT 25                            // edges per thread per chunk
#define CHUNK (256 * EPT)                 // 6400 edges per chunk
#define NCHUNK ((NE + CHUNK - 1) / CHUNK) // 125

// ---------------- degree / CSR build (XCD-partitioned by dst range) ----------------
// blockIdx % 8 -> partition -> (heuristically) one XCD; each cnt/csr line is then
// written by exactly one XCD, so lines accumulate in its L2 instead of ping-ponging.
__global__ __launch_bounds__(256) void k_count(const int* __restrict__ dst, int* __restrict__ cnt, int E) {
  int p = blockIdx.x & (NPART - 1);
  int chunk = blockIdx.x >> 3;
  int lo = p * PSIZE, hi = lo + PSIZE;
  int base = chunk * CHUNK + threadIdx.x;
#pragma unroll
  for (int i = 0; i < EPT; ++i) {
    int e = base + i * 256;
    if (e < E) {
      int d = dst[e];
      if (d >= lo && d < hi) atomicAdd(&cnt[d], 1);
    }
  }
}

__global__ __launch_bounds__(256) void k_fill(const int* __restrict__ src, const int* __restrict__ dst,
                                              int* __restrict__ cursor, int* __restrict__ csr_src, int E) {
  int p = blockIdx.x & (NPART - 1);
  int chunk = blockIdx.x >> 3;
  int lo = p * PSIZE, hi = lo + PSIZE;
  int base = chunk * CHUNK + threadIdx.x;
#pragma unroll
  for (int i = 0; i < EPT; ++i) {
    int e = base + i * 256;
    if (e < E) {
      int d = dst[e];
      if (d >= lo && d < hi) {
        int s = src[e];
        int pos = atomicAdd(&cursor[d], 1);
        csr_src[pos] = s;
      }
    }
  }
}

__global__ __launch_bounds__(256) void k_dinv(const int* __restrict__ cnt, float* __restrict__ dinv, int N) {
  int i = blockIdx.x * 256 + threadIdx.x;
  if (i < N) {
    float d = (float)(cnt[i] < 1 ? 1 : cnt[i]);
    dinv[i] = 1.0f / sqrtf(d);
  }
}

__global__ __launch_bounds__(1024) void k_scan1(const int* __restrict__ cnt, int* __restrict__ off,
                                                int* __restrict__ bsum, int N) {
  __shared__ int sh[1024];
  int t = threadIdx.x;
  int i = blockIdx.x * 1024 + t;
  int v = (i < N) ? cnt[i] : 0;
  sh[t] = v;
  __syncthreads();
  for (int d = 1; d < 1024; d <<= 1) {
    int x = (t >= d) ? sh[t - d] : 0;
    __syncthreads();
    sh[t] += x;
    __syncthreads();
  }
  if (i < N) off[i] = sh[t] - v;           // exclusive within block
  if (t == 1023) bsum[blockIdx.x] = sh[t]; // block total
}

__global__ void k_scan2(const int* __restrict__ bsum, int* __restrict__ btop, int nb) {
  if (threadIdx.x == 0 && blockIdx.x == 0) {
    int run = 0;
    for (int b = 0; b < nb; ++b) { btop[b] = run; run += bsum[b]; }
  }
}

__global__ __launch_bounds__(1024) void k_scan3(int* __restrict__ off, const int* __restrict__ btop,
                                                int* __restrict__ cursor, int N) {
  int i = blockIdx.x * 1024 + threadIdx.x;
  if (i < N) {
    int v = off[i] + btop[blockIdx.x];
    off[i] = v;
    cursor[i] = v;
  }
}

// ---------------- SpMM v2 (gather, pre-scaled compact table, 4-way edge ILP) ----------------
// Sin: [N,64] scaled features (S = dinv .* X), stride 64.
// out[n][0:64] = alpha*dinv[n]*sum_s Sin[s]  (+ beta*aux[n])   -- stride ldo (pre-offset pointer)
// out_s (optional): dinv[n] * out[n], compact [N,64].
// Wave layout: 1 wave = 1 node; lane = (g<<4)|q, g=edge group 0..3, q=col quad 0..15.
__global__ __launch_bounds__(256) void k_spmm2(const float* __restrict__ Sin,
                                               float* __restrict__ out, int ldo,
                                               float* __restrict__ out_s,
                                               const float* __restrict__ aux, int ldaux,
                                               const int* __restrict__ off, const int* __restrict__ csr_src,
                                               const float* __restrict__ dinv,
                                               float alpha, float beta, int use_aux, int N, int E) {
  int wid = (blockIdx.x * 256 + threadIdx.x) >> 6;
  if (wid >= N) return;
  int lane = threadIdx.x & 63;
  int g = lane >> 4;          // edge group
  int c4 = (lane & 15) * 4;   // column quad base
  int jb = off[wid];
  int je = (wid + 1 < N) ? off[wid + 1] : E;

  float4 acc = make_float4(0.f, 0.f, 0.f, 0.f);
  int j = jb + g;
  for (; j + 4 < je; j += 8) {
    int s0 = csr_src[j];
    int s1 = csr_src[j + 4];
    float4 v0 = *(const float4*)(Sin + (size_t)s0 * H + c4);
    float4 v1 = *(const float4*)(Sin + (size_t)s1 * H + c4);
    acc.x += v0.x + v1.x;
    acc.y += v0.y + v1.y;
    acc.z += v0.z + v1.z;
    acc.w += v0.w + v1.w;
  }
  if (j < je) {
    int s0 = csr_src[j];
    float4 v0 = *(const float4*)(Sin + (size_t)s0 * H + c4);
    acc.x += v0.x; acc.y += v0.y; acc.z += v0.z; acc.w += v0.w;
  }
#pragma unroll
  for (int o = 16; o <= 32; o <<= 1) {
    acc.x += __shfl_xor(acc.x, o);
    acc.y += __shfl_xor(acc.y, o);
    acc.z += __shfl_xor(acc.z, o);
    acc.w += __shfl_xor(acc.w, o);
  }
  if (g == 0) {
    float dn = dinv[wid];
    float a = alpha * dn;
    float4 r;
    r.x = a * acc.x; r.y = a * acc.y; r.z = a * acc.z; r.w = a * acc.w;
    if (use_aux) {
      float4 x = *(const float4*)(aux + (size_t)wid * ldaux + c4);
      r.x = fmaf(beta, x.x, r.x);
      r.y = fmaf(beta, x.y, r.y);
      r.z = fmaf(beta, x.z, r.z);
      r.w = fmaf(beta, x.w, r.w);
    }
    *(float4*)(out + (size_t)wid * ldo + c4) = r;
    if (out_s) {
      float4 rs;
      rs.x = dn * r.x; rs.y = dn * r.y; rs.z = dn * r.z; rs.w = dn * r.w;
      *(float4*)(out_s + (size_t)wid * H + c4) = rs;
    }
  }
}

// ---------------- dense GEMM: out[N,64] = act(A[N,K] @ W[64,K]^T + b) ----------------
__global__ __launch_bounds__(256) void k_gemm64(const float* __restrict__ A, int lda, int K,
                                                const float* __restrict__ W,
                                                const float* __restrict__ bias,
                                                float* __restrict__ out, int ldo,
                                                float* __restrict__ out_s,
                                                const float* __restrict__ dinv,
                                                int N, int do_relu) {
  __shared__ float As[32][68];
  __shared__ float Bs[32][64];
  const int tid = threadIdx.x;
  const int r0 = blockIdx.x * 64;
  const int tr = tid >> 4;
  const int tc = tid & 15;
  float acc[4][4] = {{0.f}};

  for (int k0 = 0; k0 < K; k0 += 32) {
#pragma unroll
    for (int q = 0; q < 2; ++q) {
      int idx = tid + q * 256;
      int row = idx >> 3;
      int jj = idx & 7;
      int gr = r0 + row;
      float4 v = make_float4(0.f, 0.f, 0.f, 0.f);
      if (gr < N) v = *(const float4*)(A + (size_t)gr * lda + k0 + jj * 4);
      As[jj * 4 + 0][row] = v.x;
      As[jj * 4 + 1][row] = v.y;
      As[jj * 4 + 2][row] = v.z;
      As[jj * 4 + 3][row] = v.w;
    }
#pragma unroll
    for (int q = 0; q < 2; ++q) {
      int idx = tid + q * 256;
      int col = idx & 63;
      int jb = idx >> 6;
      float4 v = *(const float4*)(W + (size_t)col * K + k0 + jb * 4);
      Bs[jb * 4 + 0][col] = v.x;
      Bs[jb * 4 + 1][col] = v.y;
      Bs[jb * 4 + 2][col] = v.z;
      Bs[jb * 4 + 3][col] = v.w;
    }
    __syncthreads();
#pragma unroll
    for (int kk = 0; kk < 32; ++kk) {
      float4 a = *(const float4*)(&As[kk][tr * 4]);
      float4 b = *(const float4*)(&Bs[kk][tc * 4]);
      float av[4] = {a.x, a.y, a.z, a.w};
      float bv[4] = {b.x, b.y, b.z, b.w};
#pragma unroll
      for (int i = 0; i < 4; ++i)
#pragma unroll
        for (int j = 0; j < 4; ++j) acc[i][j] = fmaf(av[i], bv[j], acc[i][j]);
    }
    __syncthreads();
  }

  float4 bb = *(const float4*)(bias + tc * 4);
  float bv[4] = {bb.x, bb.y, bb.z, bb.w};
#pragma unroll
  for (int i = 0; i < 4; ++i) {
    int row = r0 + tr * 4 + i;
    if (row < N) {
      float t0 = acc[i][0] + bv[0];
      float t1 = acc[i][1] + bv[1];
      float t2 = acc[i][2] + bv[2];
      float t3 = acc[i][3] + bv[3];
      if (do_relu) {
        t0 = fmaxf(t0, 0.f); t1 = fmaxf(t1, 0.f);
        t2 = fmaxf(t2, 0.f); t3 = fmaxf(t3, 0.f);
      }
      float4 o = make_float4(t0, t1, t2, t3);
      *(float4*)(out + (size_t)row * ldo + tc * 4) = o;
      if (out_s) {
        float dn = dinv[row];
        float4 os = make_float4(dn * t0, dn * t1, dn * t2, dn * t3);
        *(float4*)(out_s + (size_t)row * H + tc * 4) = os;
      }
    }
  }
}

// ---------------- head: out[N,2] = h[N,64] @ W4[2,64]^T + b4 ----------------
__global__ __launch_bounds__(256) void k_head(const float* __restrict__ h, int ldh,
                                              const float* __restrict__ W4, const float* __restrict__ b4,
                                              float* __restrict__ out, int N) {
  int wid = (blockIdx.x * 256 + threadIdx.x) >> 6;
  int lane = threadIdx.x & 63;
  if (wid >= N) return;
  float a = h[(size_t)wid * ldh + lane];
  float acc0 = a * W4[lane];
  float acc1 = a * W4[64 + lane];
#pragma unroll
  for (int o = 32; o > 0; o >>= 1) {
    acc0 += __shfl_xor(acc0, o);
    acc1 += __shfl_xor(acc1, o);
  }
  if (lane == 0) {
    out[(size_t)wid * 2 + 0] = acc0 + b4[0];
    out[(size_t)wid * 2 + 1] = acc1 + b4[1];
  }
}

extern "C" void kernel_launch(void* const* d_in, const int* in_sizes, int n_in,
                              void* d_out, int out_size, void* d_ws, size_t ws_size,
                              hipStream_t stream) {
  const float* in_feat = (const float*)d_in[0];
  const int* src = (const int*)d_in[1];
  const int* dst = (const int*)d_in[2];
  const float* W1 = (const float*)d_in[3];
  const float* b1 = (const float*)d_in[4];
  const float* W2 = (const float*)d_in[5];
  const float* b2 = (const float*)d_in[6];
  const float* Wc1 = (const float*)d_in[7];
  const float* bc1 = (const float*)d_in[8];
  const float* Wc2 = (const float*)d_in[9];
  const float* bc2 = (const float*)d_in[10];
  const float* W3 = (const float*)d_in[11];
  const float* b3 = (const float*)d_in[12];
  const float* W4 = (const float*)d_in[13];
  const float* b4 = (const float*)d_in[14];
  float* out = (float*)d_out;

  char* ws = (char*)d_ws;
  size_t o = 0;
  auto carve = [&](size_t bytes) -> void* {
    o = (o + 255) & ~(size_t)255;
    void* p = ws + o;
    o += bytes;
    return p;
  };
  int* cnt = (int*)carve((size_t)NN * 4);
  int* off = (int*)carve((size_t)NN * 4);
  int* cursor = (int*)carve((size_t)NN * 4);
  int* bsum = (int*)carve(64 * 4);
  int* btop = (int*)carve(64 * 4);
  int* csr_src = (int*)carve((size_t)NE * 4);
  float* dinv = (float*)carve((size_t)NN * 4);
  float* h1 = (float*)carve((size_t)NN * H * 4);
  float* h2 = (float*)carve((size_t)NN * H * 4);
  float* S0 = (float*)carve((size_t)NN * H * 4);
  float* S1 = (float*)carve((size_t)NN * H * 4);
  float* X1buf = (float*)carve((size_t)NN * 3 * H * 4);
  float* X2buf = (float*)carve((size_t)NN * 3 * H * 4);
  (void)ws_size; (void)in_sizes; (void)n_in; (void)out_size;

  const int NB_N = (NN + 255) / 256;
  const int NB_S = (NN + 1023) / 1024;
  const int NB_W = (NN * 64 + 255) / 256; // wave-per-node: 12500
  const int NB_G = (NN + 63) / 64;        // 782
  const int NB_P = NCHUNK * NPART;        // 1000 partitioned-CSR blocks

  // degree + dinv + CSR (XCD-partitioned count/fill)
  hipMemsetAsync(cnt, 0, (size_t)NN * 4, stream);
  k_count<<<NB_P, 256, 0, stream>>>(dst, cnt, NE);
  k_dinv<<<NB_N, 256, 0, stream>>>(cnt, dinv, NN);
  k_scan1<<<NB_S, 1024, 0, stream>>>(cnt, off, bsum, NN);
  k_scan2<<<1, 64, 0, stream>>>(bsum, btop, NB_S);
  k_scan3<<<NB_S, 1024, 0, stream>>>(off, btop, cursor, NN);
  k_fill<<<NB_P, 256, 0, stream>>>(src, dst, cursor, csr_src, NE);

  // h1 = relu(in_feat @ W1^T + b1)
  k_gemm64<<<NB_G, 256, 0, stream>>>(in_feat, INF, INF, W1, b1, h1, H,
                                     (float*)nullptr, dinv, NN, 1);
  // X0 = relu(h1 @ W2^T + b2) -> X1buf[:,0:64]; scaled -> S0
  k_gemm64<<<NB_G, 256, 0, stream>>>(h1, H, H, W2, b2, X1buf, 3 * H, S0, dinv, NN, 1);
  // X1 = -A.X0 -> X1buf[:,64:128]; scaled -> S1
  k_spmm2<<<NB_W, 256, 0, stream>>>(S0, X1buf + H, 3 * H, S1, (const float*)nullptr, 0,
                                    off, csr_src, dinv, -1.f, 0.f, 0, NN, NE);
  // X2 = -2*A.X1 - X0 -> X1buf[:,128:192]
  k_spmm2<<<NB_W, 256, 0, stream>>>(S1, X1buf + 2 * H, 3 * H, (float*)nullptr, X1buf, 3 * H,
                                    off, csr_src, dinv, -2.f, -1.f, 1, NN, NE);
  // conv1 linear: relu(X1buf @ Wc1^T + bc1) -> X2buf[:,0:64]; scaled -> S0
  k_gemm64<<<NB_G, 256, 0, stream>>>(X1buf, 3 * H, 3 * H, Wc1, bc1, X2buf, 3 * H, S0, dinv, NN, 1);
  // conv2 terms
  k_spmm2<<<NB_W, 256, 0, stream>>>(S0, X2buf + H, 3 * H, S1, (const float*)nullptr, 0,
                                    off, csr_src, dinv, -1.f, 0.f, 0, NN, NE);
  k_spmm2<<<NB_W, 256, 0, stream>>>(S1, X2buf + 2 * H, 3 * H, (float*)nullptr, X2buf, 3 * H,
                                    off, csr_src, dinv, -2.f, -1.f, 1, NN, NE);
  // conv2 linear -> h1
  k_gemm64<<<NB_G, 256, 0, stream>>>(X2buf, 3 * H, 3 * H, Wc2, bc2, h1, H,
                                     (float*)nullptr, dinv, NN, 1);
  // h2 = relu(h1 @ W3^T + b3)
  k_gemm64<<<NB_G, 256, 0, stream>>>(h1, H, H, W3, b3, h2, H,
                                     (float*)nullptr, dinv, NN, 1);
  // head
  k_head<<<NB_W, 256, 0, stream>>>(h2, H, W4, b4, out, NN);
}